// Round 15
// baseline (204.665 us; speedup 1.0000x reference)
//
#include <hip/hip_runtime.h>

#define NB 17340      // 15*34*34
#define TOPK1 3000
#define TOPK2 300
#define PTS 304       // pooledT row stride

__constant__ float c_AW[15] = {9.232984, 16.0, 27.712813, 18.465969, 32.0, 55.425626,
                               36.931937, 64.0, 110.851252, 73.863875, 128.0, 221.702503,
                               147.72775, 256.0, 443.405007};
__constant__ float c_AH[15] = {27.72668, 16.0, 9.237604, 55.453359, 32.0, 18.475209,
                               110.906719, 64.0, 36.950417, 221.813438, 128.0, 73.900834,
                               443.626876, 256.0, 147.801669};

__device__ __forceinline__ unsigned mapf(float f) {
  unsigned u = __float_as_uint(f);
  return (u & 0x80000000u) ? ~u : (u | 0x80000000u);
}
__device__ __forceinline__ float unmapf(unsigned m) {
  unsigned u = (m & 0x80000000u) ? (m & 0x7FFFFFFFu) : ~m;
  return __uint_as_float(u);
}
__device__ __forceinline__ float clipc(float v) {
  return fminf(fmaxf(v, 0.0f), 269.0f);
}
// uniform-lane 64-bit broadcast: SALU v_readlane, NOT ds_bpermute (lane must be uniform)
__device__ __forceinline__ unsigned long long readlane64(unsigned long long v, int lane) {
  unsigned lo = (unsigned)__builtin_amdgcn_readlane((int)(unsigned)v, lane);
  unsigned hi = (unsigned)__builtin_amdgcn_readlane((int)(unsigned)(v >> 32), lane);
  return ((unsigned long long)hi << 32) | lo;
}

// ---------------- Kernel 1: RPN decode + keep filter + global histogram ----------------
__global__ void k_decode(const float* __restrict__ cls, const float* __restrict__ pred,
                         float* __restrict__ boxes, float* __restrict__ scores,
                         unsigned int* __restrict__ hist) {
  int i = blockIdx.x * 256 + threadIdx.x;
  if (i >= NB) return;
  int a = i / 1156;
  int rem = i - a * 1156;
  int y = rem / 34;
  int x = rem - y * 34;
  float fg = cls[(15 + a) * 1156 + rem];
  const float* p = pred + a * 4 * 1156 + rem;
  float t0 = p[0]    * (float)0.12677  + (float)0.000437;
  float t1 = p[1156] * (float)0.095741 + (float)0.002586;
  float t2 = p[2312] * (float)0.3173   + (float)-0.123953;
  float t3 = p[3468] * (float)0.281042 + (float)-0.081469;
  float aw = c_AW[a], ah = c_AH[a];
  float cx = t0 * aw + (float)x * 8.0f;
  float cy = t1 * ah + (float)y * 8.0f;
  float bw = expf(t2) * aw;
  float bh = expf(t3) * ah;
  float x1 = clipc(cx - 0.5f * (bw - 1.0f));
  float y1 = clipc(cy - 0.5f * (bh - 1.0f));
  float x2 = clipc(cx + 0.5f * (bw - 1.0f));
  float y2 = clipc(cy + 0.5f * (bh - 1.0f));
  boxes[i * 4 + 0] = x1;
  boxes[i * 4 + 1] = y1;
  boxes[i * 4 + 2] = x2;
  boxes[i * 4 + 3] = y2;
  float w2 = x2 - x1 + 1.0f, h2 = y2 - y1 + 1.0f;
  bool keep = (fg >= 0.2f) && ((w2 >= (float)6.16056) || (h2 >= (float)6.16056));
  scores[i] = keep ? fg : -1.0f;
  if (keep) atomicAdd(&hist[mapf(fg) >> 18], 1u);
}

// ---------------- Kernel 2a: cutoff bucket (single block) ----------------
__global__ __launch_bounds__(256) void k_cutoff(const unsigned int* __restrict__ hist,
                                                unsigned int* __restrict__ bcut) {
  const int t = threadIdx.x;
  __shared__ unsigned int sh[16384];
  __shared__ unsigned int coarse[256];
  for (int i = t; i < 16384; i += 256) sh[i] = hist[i];
  __syncthreads();
  {
    unsigned s = 0;
    int b0 = t * 64;
    for (int b = 0; b < 64; ++b) s += sh[b0 + b];
    coarse[t] = s;
  }
  __syncthreads();
  if (t == 0) {
    unsigned acc = 0, nbefore = 0;
    int C = 0;
    for (int c = 255; c >= 0; --c) {
      if (acc + coarse[c] >= (unsigned)TOPK1) { C = c; nbefore = acc; break; }
      acc += coarse[c];
    }
    unsigned acc2 = nbefore;
    int B = C * 64;
    for (int b = C * 64 + 63; b >= C * 64; --b) {
      if (acc2 + sh[b] >= (unsigned)TOPK1) { B = b; break; }
      acc2 += sh[b];
    }
    bcut[0] = (unsigned)B;
  }
}

// ---------------- Kernel 2b: parallel compact (no hist staging) ----------------
__global__ __launch_bounds__(256) void k_compact(const float* __restrict__ scores,
                                                 const unsigned int* __restrict__ bcut,
                                                 unsigned int* __restrict__ cnt,
                                                 unsigned long long* __restrict__ keys) {
  int i = blockIdx.x * 256 + threadIdx.x;
  const unsigned B = bcut[0];
  if (i < NB) {
    unsigned m = mapf(scores[i]);
    if ((m >> 18) >= B) {
      unsigned p = atomicAdd(cnt, 1u);
      if (p < 4096u) keys[p] = ((unsigned long long)m << 15) | (unsigned)(32767 - i);
    }
  }
}

// ---------------- Kernel 3: exact rank-by-count sort (128 blocks, 8 lanes/key) ------------
__global__ __launch_bounds__(256) void k_sort(const float* __restrict__ boxes,
                                              const unsigned int* __restrict__ cnt,
                                              const unsigned long long* __restrict__ keys,
                                              unsigned int* __restrict__ sscore,
                                              float4* __restrict__ sbox) {
  const int t = threadIdx.x;
  __shared__ unsigned long long lk[4096];
  const int K = min((int)cnt[0], 4096);
  for (int i = t; i < 4096; i += 256) lk[i] = (i < K) ? keys[i] : 0ull;
  __syncthreads();
  int p = blockIdx.x * 32 + (t >> 3);   // 8 lanes per key, 32 keys per block
  const int s = t & 7;
  if (p < K) {
    unsigned long long kp = lk[p];
    int r = 0;
    for (int q = s; q < 4096; q += 64) {   // 64 fixed iterations
#pragma unroll
      for (int u = 0; u < 8; ++u) r += (lk[q + 8 * u] > kp) ? 1 : 0;
    }
    r += __shfl_xor(r, 1);
    r += __shfl_xor(r, 2);
    r += __shfl_xor(r, 4);
    if (s == 0 && r < TOPK1) {
      int idx = 32767 - (int)(kp & 32767ull);
      sscore[r] = (unsigned)(kp >> 15);
      sbox[r] = ((const float4*)boxes)[idx];
    }
  }
}

// ---------------- Kernel 4: IoU suppression bitmap (all CUs) ----------------
__global__ __launch_bounds__(64) void k_iou(const float4* __restrict__ sbox,
                                            unsigned long long* __restrict__ mat) {
  const int wi = blockIdx.x, wj = blockIdx.y;
  if (wj < wi) return;
  __shared__ float4 cb[64];
  __shared__ float car[64];
  const int l = threadIdx.x;
  float4 c = sbox[wj * 64 + l];
  cb[l] = c;
  car[l] = (c.z - c.x + 1.0f) * (c.w - c.y + 1.0f);
  __syncthreads();
  const int ri = wi * 64 + l;
  float4 r = sbox[ri];
  float rar = (r.z - r.x + 1.0f) * (r.w - r.y + 1.0f);
  unsigned long long m = 0ull;
#pragma unroll 16
  for (int j = 0; j < 64; ++j) {
    float4 cc = cb[j];
    float iw = fmaxf(fminf(r.z, cc.z) - fmaxf(r.x, cc.x) + 1.0f, 0.0f);
    float ih = fmaxf(fminf(r.w, cc.w) - fmaxf(r.y, cc.y) + 1.0f, 0.0f);
    float inter = iw * ih;
    float iou = inter / (car[j] + rar - inter);
    if (iou > 0.7f) m |= (1ull << j);
  }
  mat[ri * 48 + wj] = m;
}

// ---------------- Kernel 5: bitmap greedy NMS-300, SALU accept chain ----------------
// Per chunk: lane l preloads its own row's diagonal word (rowbuf[l][c]); per accept the
// kill word is readlane64(diag, j) -- pure SALU, no LDS on the accept chain. run-update
// reads are batched 4-deep after the accept loop. Values identical to prior rounds.
__global__ __launch_bounds__(256) void k_nms1(const unsigned int* __restrict__ sscore,
                                              const float4* __restrict__ sbox,
                                              const unsigned long long* __restrict__ mat,
                                              float* __restrict__ dout,
                                              float* __restrict__ rois_xy,
                                              float* __restrict__ validf) {
  const int t = threadIdx.x;
  __shared__ unsigned long long rowbuf[2][64][48];   // 49152 B
  __shared__ unsigned int sc[3008];
  __shared__ int arank[300];
  __shared__ int s_A;
  for (int i = t; i < 3008; i += 256) sc[i] = (i < TOPK1) ? sscore[i] : 0u;
  if (t == 0) s_A = 0;

  // prologue: all threads stage chunk 0
  {
    unsigned long long r0v[12];
#pragma unroll
    for (int i = 0; i < 12; ++i) r0v[i] = mat[t + 256 * i];
#pragma unroll
    for (int i = 0; i < 12; ++i) {
      int idx = t + 256 * i;
      rowbuf[0][idx / 48][idx % 48] = r0v[i];
    }
  }
  // staging waves pre-issue chunk 1 (rgA: odd chunks) and chunk 2 (rgB: even chunks)
  unsigned long long rgA[16], rgB[16];
  const int st = t - 64;
  if (t >= 64) {
#pragma unroll
    for (int i = 0; i < 16; ++i) rgA[i] = mat[1 * 3072 + st + 192 * i];
#pragma unroll
    for (int i = 0; i < 16; ++i) rgB[i] = mat[2 * 3072 + st + 192 * i];
  }
  __syncthreads();

  unsigned long long run = 0ull;   // wave0: lane w holds running-suppression word w
  int A = 0;
  const int l = t & 63;
  const int lw = (l < 48) ? l : 0;  // clamp for LDS row reads (words 48..63 unused)
  for (int c = 0; c < 47; ++c) {
    if (t < 64) {
      const bool okw = (l >= c) && (l < 47);
      const int buf = c & 1;
      unsigned long long diag = rowbuf[buf][l][c];   // row l word c (parallel, off-chain)
      unsigned long long supw = readlane64(run, c);
      bool aliveb = (sc[c * 64 + l] > 0x80000000u) && !((supw >> l) & 1ull);
      unsigned long long alive = __ballot(aliveb);   // wave-uniform alive mask
      unsigned long long accm = 0ull;
      int Aw = A;
      while (alive != 0ull && Aw < 300) {            // pure SALU chain
        int j = __ffsll((long long)alive) - 1;       // highest key
        if (l == 0) arank[Aw] = c * 64 + j;
        Aw++;
        accm |= (1ull << j);
        unsigned long long kill = readlane64(diag, j);  // == mat[j][word c]; self-bit kills j
        alive &= ~kill;
      }
      // batched run update: 4 independent LDS reads per wait
      while (accm != 0ull) {
        int j1 = __ffsll((long long)accm) - 1;
        unsigned long long m2 = accm & (accm - 1ull);
        int j2 = (m2 != 0ull) ? (__ffsll((long long)m2) - 1) : j1;
        unsigned long long m3 = (m2 != 0ull) ? (m2 & (m2 - 1ull)) : 0ull;
        int j3 = (m3 != 0ull) ? (__ffsll((long long)m3) - 1) : j1;
        unsigned long long m4 = (m3 != 0ull) ? (m3 & (m3 - 1ull)) : 0ull;
        int j4 = (m4 != 0ull) ? (__ffsll((long long)m4) - 1) : j1;
        unsigned long long v1 = rowbuf[buf][j1][lw];
        unsigned long long v2 = rowbuf[buf][j2][lw];
        unsigned long long v3 = rowbuf[buf][j3][lw];
        unsigned long long v4 = rowbuf[buf][j4][lw];
        unsigned long long o = v1;
        if (m2 != 0ull) o |= v2;
        if (m3 != 0ull) o |= v3;
        if (m4 != 0ull) o |= v4;
        if (okw) run |= o;
        accm = (m4 != 0ull) ? (m4 & (m4 - 1ull)) : 0ull;
      }
      A = Aw;
      if (l == 0) s_A = Aw;
    } else if (c < 46) {
      // write chunk c+1; re-issue same register set for chunk c+3
      int nb = (c + 1) & 1;
      if (((c + 1) & 1) == 1) {   // odd chunk -> rgA
#pragma unroll
        for (int i = 0; i < 16; ++i) {
          int idx = st + 192 * i;
          rowbuf[nb][idx / 48][idx % 48] = rgA[i];
        }
        if (c + 3 <= 46) {
#pragma unroll
          for (int i = 0; i < 16; ++i) rgA[i] = mat[(c + 3) * 3072 + st + 192 * i];
        }
      } else {                    // even chunk -> rgB
#pragma unroll
        for (int i = 0; i < 16; ++i) {
          int idx = st + 192 * i;
          rowbuf[nb][idx / 48][idx % 48] = rgB[i];
        }
        if (c + 3 <= 46) {
#pragma unroll
          for (int i = 0; i < 16; ++i) rgB[i] = mat[(c + 3) * 3072 + st + 192 * i];
        }
      }
    }
    __syncthreads();
    A = s_A;
    if (A >= 300) break;
    if (c < 46 && sc[(c + 1) * 64] <= 0x80000000u) break;  // rest invalid
  }
  // parallel write-back
  for (int a = t; a < A; a += 256) {
    int rk = arank[a];
    float4 b = sbox[rk];
    dout[30 + a * 5 + 0] = 0.0f;
    dout[30 + a * 5 + 1] = b.x;
    dout[30 + a * 5 + 2] = b.y;
    dout[30 + a * 5 + 3] = b.z;
    dout[30 + a * 5 + 4] = b.w;
    dout[1530 + a] = unmapf(sc[rk]);
    rois_xy[a * 4 + 0] = b.x; rois_xy[a * 4 + 1] = b.y;
    rois_xy[a * 4 + 2] = b.z; rois_xy[a * 4 + 3] = b.w;
    validf[a] = 1.0f;
  }
  for (int z = 30 + A * 5 + t; z < 1530; z += 256) dout[z] = 0.f;
  for (int z = 1530 + A + t; z < 1830; z += 256) dout[z] = 0.f;
  for (int z = A * 4 + t; z < 1200; z += 256) rois_xy[z] = 0.f;
  for (int z = A + t; z < 300; z += 256) validf[z] = 0.f;
}

// ---------------- Kernel 6: PSROI pooling with hoisted coordinate tables ----------------
__global__ __launch_bounds__(256) void k_psroi(const float* __restrict__ ft,
                                               const float* __restrict__ rois_xy,
                                               float* __restrict__ pooledT) {
  int r = blockIdx.x;
  __shared__ int2 ycs[28];
  __shared__ float2 wys[28];
  __shared__ int2 xcs[28];
  __shared__ float2 wxs[28];
  float r0 = rois_xy[r * 4 + 0], r1 = rois_xy[r * 4 + 1];
  float r2 = rois_xy[r * 4 + 2], r3 = rois_xy[r * 4 + 3];
  float sw = r0 * 0.125f;
  float sh = r1 * 0.125f;
  float ew = (r2 + 1.0f) * 0.125f;
  float eh = (r3 + 1.0f) * 0.125f;
  float rh = fmaxf(eh - sh, 0.1f);
  float rw = fmaxf(ew - sw, 0.1f);
  float bh = rh / 7.0f;
  float bwd = rw / 7.0f;
  const int t = threadIdx.x;
  if (t < 28) {
    int p = t >> 2, sy = t & 3;
    float ys = sh + (float)p * bh + ((float)sy + 0.5f) * (bh * 0.25f);
    float y0f = floorf(ys);
    float dy = ys - y0f;
    int y0 = (int)y0f;
    float wy0 = (1.0f - dy) * ((y0 >= 0 && y0 < 34) ? 1.f : 0.f);
    float wy1 = dy * ((y0 + 1 >= 0 && y0 + 1 < 34) ? 1.f : 0.f);
    ycs[t] = make_int2(min(max(y0, 0), 33), min(max(y0 + 1, 0), 33));
    wys[t] = make_float2(wy0, wy1);
  } else if (t >= 32 && t < 60) {
    int q = (t - 32) >> 2, sx = (t - 32) & 3;
    float xs = sw + (float)q * bwd + ((float)sx + 0.5f) * (bwd * 0.25f);
    float x0f = floorf(xs);
    float dx = xs - x0f;
    int x0 = (int)x0f;
    float wx0 = (1.0f - dx) * ((x0 >= 0 && x0 < 34) ? 1.f : 0.f);
    float wx1 = dx * ((x0 + 1 >= 0 && x0 + 1 < 34) ? 1.f : 0.f);
    xcs[t - 32] = make_int2(min(max(x0, 0), 33), min(max(x0 + 1, 0), 33));
    wxs[t - 32] = make_float2(wx0, wx1);
  }
  __syncthreads();
  for (int o = t; o < 490; o += 256) {
    int pq = o % 49;
    int p = pq / 7, q = pq - p * 7;
    const float* base = ft + o * 1156;
    float acc = 0.f;
#pragma unroll
    for (int sy = 0; sy < 4; ++sy) {
      int2 yc = ycs[p * 4 + sy];
      float2 wy = wys[p * 4 + sy];
#pragma unroll
      for (int sx = 0; sx < 4; ++sx) {
        int2 xc = xcs[q * 4 + sx];
        float2 wx = wxs[q * 4 + sx];
        float v00 = base[yc.x * 34 + xc.x], v01 = base[yc.x * 34 + xc.y];
        float v10 = base[yc.y * 34 + xc.x], v11 = base[yc.y * 34 + xc.y];
        acc += wy.x * wx.x * v00 + wy.x * wx.y * v01 + wy.y * wx.x * v10 + wy.y * wx.y * v11;
      }
    }
    pooledT[o * PTS + r] = acc * (1.0f / 16.0f);
  }
}

// ---------------- Kernel 7: FC1 GEMM 64x32 tiles (320 blocks), 1 barrier/step -------------
// xcd = b&7, s = b>>3: o_tile = xcd + 8*(s/5) in 0..63 (32 cols), r_tile = s%5. The 5 blocks
// sharing an out-tile's weights land on one XCD. Per-element k-order unchanged (bitwise-same).
__global__ __launch_bounds__(256) void k_fc1(const float* __restrict__ pooledT,
                                             const float* __restrict__ Wi,
                                             const float* __restrict__ bi,
                                             float* __restrict__ feat) {
  __shared__ float As[2][32][68];
  __shared__ float Bs[2][32][36];   // [kk][oo], pad 36
  const int t = threadIdx.x;
  const int tr = t >> 4, tc = t & 15;          // 16x16 thread grid
  const int b = blockIdx.x;
  const int xcd = b & 7, s = b >> 3;
  const int r0 = (s % 5) * 64;                 // roi tile
  const int o0 = (xcd + 8 * (s / 5)) * 32;     // out tile of 32 cols
  float acc[4][2];
#pragma unroll
  for (int i = 0; i < 4; ++i) { acc[i][0] = 0.f; acc[i][1] = 0.f; }
  float ra[8], rb[4];

#pragma unroll
  for (int i = 0; i < 8; ++i) {
    int idx = t + 256 * i;
    int kk = idx >> 6, rr = idx & 63;
    ra[i] = (kk < 490 && r0 + rr < 300) ? pooledT[kk * PTS + r0 + rr] : 0.f;
  }
#pragma unroll
  for (int i = 0; i < 4; ++i) {
    int idx = t + 256 * i;
    int oo = idx >> 5, k2 = idx & 31;
    rb[i] = Wi[(o0 + oo) * 490 + k2];
  }
#pragma unroll
  for (int i = 0; i < 8; ++i) {
    int idx = t + 256 * i;
    As[0][idx >> 6][idx & 63] = ra[i];
  }
#pragma unroll
  for (int i = 0; i < 4; ++i) {
    int idx = t + 256 * i;
    Bs[0][idx & 31][idx >> 5] = rb[i];         // [kk][oo]
  }
  __syncthreads();

  int cur = 0;
  for (int step = 0; step < 16; ++step) {
    if (step < 15) {
      int k0n = (step + 1) * 32;
#pragma unroll
      for (int i = 0; i < 8; ++i) {
        int idx = t + 256 * i;
        int kk = idx >> 6, rr = idx & 63;
        int k = k0n + kk;
        ra[i] = (k < 490 && r0 + rr < 300) ? pooledT[k * PTS + r0 + rr] : 0.f;
      }
#pragma unroll
      for (int i = 0; i < 4; ++i) {
        int idx = t + 256 * i;
        int oo = idx >> 5, k2 = k0n + (idx & 31);
        rb[i] = (k2 < 490) ? Wi[(o0 + oo) * 490 + k2] : 0.f;
      }
    }
#pragma unroll
    for (int kk = 0; kk < 32; ++kk) {
      float4 a4 = *(const float4*)&As[cur][kk][tr * 4];
      float2 b2 = *(const float2*)&Bs[cur][kk][tc * 2];
      acc[0][0] += a4.x * b2.x; acc[0][1] += a4.x * b2.y;
      acc[1][0] += a4.y * b2.x; acc[1][1] += a4.y * b2.y;
      acc[2][0] += a4.z * b2.x; acc[2][1] += a4.z * b2.y;
      acc[3][0] += a4.w * b2.x; acc[3][1] += a4.w * b2.y;
    }
    if (step < 15) {
      int nxt = cur ^ 1;
#pragma unroll
      for (int i = 0; i < 8; ++i) {
        int idx = t + 256 * i;
        As[nxt][idx >> 6][idx & 63] = ra[i];
      }
#pragma unroll
      for (int i = 0; i < 4; ++i) {
        int idx = t + 256 * i;
        Bs[nxt][idx & 31][idx >> 5] = rb[i];
      }
      cur = nxt;
    }
    __syncthreads();   // single barrier per step (writes to nxt can't alias reads of cur)
  }
  float2 bias = *(const float2*)&bi[o0 + tc * 2];
#pragma unroll
  for (int i = 0; i < 4; ++i) {
    int r = r0 + tr * 4 + i;
    if (r < 300) {
      float2 v;
      v.x = fmaxf(acc[i][0] + bias.x, 0.f);
      v.y = fmaxf(acc[i][1] + bias.y, 0.f);
      *(float2*)&feat[r * 2048 + o0 + tc * 2] = v;
    }
  }
}

// ---------------- Kernel 8: FC2 heads + softmax + per-class decode (fused) ----------------
__global__ __launch_bounds__(256) void k_fc2(const float* __restrict__ feat,
                                             const float* __restrict__ Wc,
                                             const float* __restrict__ bc,
                                             const float* __restrict__ Wb,
                                             const float* __restrict__ bb,
                                             const float* __restrict__ rois_xy,
                                             const float* __restrict__ validf,
                                             float* __restrict__ db2,
                                             float* __restrict__ msc2) {
  int r = blockIdx.x;
  int t = threadIdx.x;
  int l = t & 63, w = t >> 6;
  __shared__ float frow[2048];
  __shared__ float s_logit[20];
  __shared__ float s_probs[4];
  for (int i = t; i < 512; i += 256)
    ((float4*)frow)[i] = ((const float4*)(feat + r * 2048))[i];
  __syncthreads();
  for (int o = w; o < 20; o += 4) {
    const float* wr = (o < 4) ? (Wc + o * 2048) : (Wb + (o - 4) * 2048);
    float p = 0.f;
#pragma unroll
    for (int j = 0; j < 8; ++j) {
      float4 wv = ((const float4*)wr)[l + 64 * j];
      float4 fv = ((const float4*)frow)[l + 64 * j];
      p += wv.x * fv.x + wv.y * fv.y + wv.z * fv.z + wv.w * fv.w;
    }
    for (int off = 32; off > 0; off >>= 1) p += __shfl_xor(p, off);
    if (l == 0) s_logit[o] = p + ((o < 4) ? bc[o] : bb[o - 4]);
  }
  __syncthreads();
  if (t == 0) {
    float m = fmaxf(fmaxf(s_logit[0], s_logit[1]), fmaxf(s_logit[2], s_logit[3]));
    float e0 = expf(s_logit[0] - m), e1 = expf(s_logit[1] - m);
    float e2 = expf(s_logit[2] - m), e3 = expf(s_logit[3] - m);
    float ssum = e0 + e1 + e2 + e3;
    s_probs[0] = e0 / ssum; s_probs[1] = e1 / ssum;
    s_probs[2] = e2 / ssum; s_probs[3] = e3 / ssum;
  }
  __syncthreads();
  if (t < 3) {
    int c = t + 1;
    float x1 = rois_xy[r * 4 + 0], y1 = rois_xy[r * 4 + 1];
    float x2 = rois_xy[r * 4 + 2], y2 = rois_xy[r * 4 + 3];
    float rwv = x2 - x1 + 1.0f, rhv = y2 - y1 + 1.0f;
    float rcx = x1 + 0.5f * (rwv - 1.0f), rcy = y1 + 0.5f * (rhv - 1.0f);
    float t0 = s_logit[4 + 4 * c + 0] * 0.1f;
    float t1 = s_logit[4 + 4 * c + 1] * 0.1f;
    float t2 = s_logit[4 + 4 * c + 2] * 0.2f;
    float t3 = s_logit[4 + 4 * c + 3] * 0.2f;
    float cx = t0 * rwv + rcx, cy = t1 * rhv + rcy;
    float bw = expf(t2) * rwv, bh = expf(t3) * rhv;
    float dx1 = clipc(cx - 0.5f * (bw - 1.0f));
    float dy1 = clipc(cy - 0.5f * (bh - 1.0f));
    float dx2 = clipc(cx + 0.5f * (bw - 1.0f));
    float dy2 = clipc(cy + 0.5f * (bh - 1.0f));
    float dw = dx2 - dx1 + 1.0f, dh = dy2 - dy1 + 1.0f;
    float sc = s_probs[c];
    bool objok = (1.0f - s_probs[0]) >= 0.1f;
    bool valid = validf[r] > 0.5f;
    bool kf = valid && objok && (sc >= 0.1f) && ((dw >= (float)8.8008) || (dh >= (float)8.8008));
    int i2 = (c - 1) * 300 + r;
    db2[i2 * 4 + 0] = dx1; db2[i2 * 4 + 1] = dy1;
    db2[i2 * 4 + 2] = dx2; db2[i2 * 4 + 3] = dy2;
    msc2[i2] = kf ? sc : -1.0f;
  }
}

// ---------------- Kernel 9: rank-sort 900 (padded, unrolled) + greedy NMS-5 ----------------
__global__ __launch_bounds__(1024) void k_nms2(const float* __restrict__ db2,
                                               const float* __restrict__ msc2,
                                               float* __restrict__ dout) {
  const int t = threadIdx.x;
  __shared__ unsigned long long lk[1024];
  __shared__ unsigned long long sk[1024];
  __shared__ float4 abox[5];
  __shared__ float aar[5];
  __shared__ int s_A;
  sk[t] = 0ull;
  lk[t] = (t < 900) ? (((unsigned long long)mapf(msc2[t]) << 10) | (unsigned)(1023 - t)) : 0ull;
  if (t == 0) s_A = 0;
  __syncthreads();
  if (t < 900) {
    unsigned long long kp = lk[t];
    int r = 0;
#pragma unroll 8
    for (int q = 0; q < 1024; ++q) r += (lk[q] > kp) ? 1 : 0;   // zero pads contribute 0
    sk[r] = kp;   // keys unique -> ranks unique
  }
  __syncthreads();
  if (t < 64) {
    int A = 0;
    for (int base = 0; base < TOPK2 && A < 5; base += 64) {
      unsigned headm = (unsigned)(sk[base] >> 10);
      if (headm <= 0x80000000u) break;
      int rank = base + t;
      unsigned long long key = sk[rank];
      unsigned mk = (unsigned)(key >> 10);
      bool active = (rank < TOPK2) && (mk > 0x80000000u);
      int idx = 1023 - (int)(key & 1023ull);
      float4 bx = make_float4(0.f, 0.f, 0.f, 0.f);
      float area = 0.f;
      if (active) {
        bx = ((const float4*)db2)[idx];
        area = (bx.z - bx.x + 1.0f) * (bx.w - bx.y + 1.0f);
      }
      bool alive = active;
      for (int a = 0; a < A; ++a) {
        float4 ab = abox[a];
        float iw = fmaxf(fminf(bx.z, ab.z) - fmaxf(bx.x, ab.x) + 1.0f, 0.0f);
        float ih = fmaxf(fminf(bx.w, ab.w) - fmaxf(bx.y, ab.y) + 1.0f, 0.0f);
        float inter = iw * ih;
        float iou = inter / (area + aar[a] - inter);
        if (iou > 0.5f) { alive = false; break; }
      }
      unsigned long long bal = __ballot(alive);
      while (bal != 0ull && A < 5) {
        int j = __ffsll((long long)bal) - 1;
        float jx1 = __shfl(bx.x, j), jy1 = __shfl(bx.y, j);
        float jx2 = __shfl(bx.z, j), jy2 = __shfl(bx.w, j);
        float jar = __shfl(area, j);
        if (t == j) {
          abox[A] = bx; aar[A] = area;
          dout[A * 6 + 0] = bx.x; dout[A * 6 + 1] = bx.y;
          dout[A * 6 + 2] = bx.z; dout[A * 6 + 3] = bx.w;
          dout[A * 6 + 4] = unmapf(mk);
          dout[A * 6 + 5] = (float)(idx / 300 + 1);
        }
        if (alive) {
          float iw = fmaxf(fminf(bx.z, jx2) - fmaxf(bx.x, jx1) + 1.0f, 0.0f);
          float ih = fmaxf(fminf(bx.w, jy2) - fmaxf(bx.y, jy1) + 1.0f, 0.0f);
          float inter = iw * ih;
          float iou = inter / (area + jar - inter);
          if (iou > 0.5f || t == j) alive = false;
        }
        A++;
        bal = __ballot(alive);
      }
    }
    if (t == 0) s_A = A;
  }
  __syncthreads();
  int A = s_A;
  for (int z = A * 6 + t; z < 30; z += 1024) dout[z] = 0.f;
}

extern "C" void kernel_launch(void* const* d_in, const int* in_sizes, int n_in,
                              void* d_out, int out_size, void* d_ws, size_t ws_size,
                              hipStream_t stream) {
  const float* cls  = (const float*)d_in[0];
  const float* pred = (const float*)d_in[1];
  const float* ft   = (const float*)d_in[2];
  const float* Wi   = (const float*)d_in[3];
  const float* bi   = (const float*)d_in[4];
  const float* Wc   = (const float*)d_in[5];
  const float* bc   = (const float*)d_in[6];
  const float* Wb   = (const float*)d_in[7];
  const float* bb   = (const float*)d_in[8];
  float* out = (float*)d_out;
  float* w = (float*)d_ws;
  // layout (float offsets)
  float* boxes   = w;                                   // 0      .. 69360
  float* scores  = w + 69360;                           // 69360  .. 86700
  unsigned int* hist = (unsigned int*)(w + 86700);      // 86700  .. 103084
  unsigned int* cnt  = (unsigned int*)(w + 103084);     // 103084
  unsigned int* bcut = (unsigned int*)(w + 103085);     // 103085 (written by k_cutoff)
  unsigned long long* keys = (unsigned long long*)(w + 103088); // 4096 u64 -> 111280
  unsigned int* sscore = (unsigned int*)(w + 111280);   // 3000 u32 -> 114280
  float4* sbox   = (float4*)(w + 114280);               // 3008 f4 (padded) -> 126312
  float* rois_xy = w + 126312;                          // .. 127512
  float* validf  = w + 127512;                          // .. 127812
  float* pooledT = w + 127812;                          // 490*304=148960 -> 276772
  float* feat    = w + 276772;                          // 300*2048 -> 891172 (16B aligned)
  unsigned long long* mat = (unsigned long long*)(w + 276772); // aliases feat: 3008*48 u64
  float* db2     = w + 891172;                          // .. 894772 (16B aligned)
  float* msc2    = w + 894772;                          // .. 895672 (~3.58 MB)

  hipMemsetAsync(hist, 0, 16385 * sizeof(unsigned int), stream);  // hist + cnt
  k_decode<<<68, 256, 0, stream>>>(cls, pred, boxes, scores, hist);
  k_cutoff<<<1, 256, 0, stream>>>(hist, bcut);
  k_compact<<<68, 256, 0, stream>>>(scores, bcut, cnt, keys);
  k_sort<<<128, 256, 0, stream>>>(boxes, cnt, keys, sscore, sbox);
  k_iou<<<dim3(47, 47), 64, 0, stream>>>(sbox, mat);
  k_nms1<<<1, 256, 0, stream>>>(sscore, sbox, mat, out, rois_xy, validf);
  k_psroi<<<300, 256, 0, stream>>>(ft, rois_xy, pooledT);
  k_fc1<<<320, 256, 0, stream>>>(pooledT, Wi, bi, feat);
  k_fc2<<<300, 256, 0, stream>>>(feat, Wc, bc, Wb, bb, rois_xy, validf, db2, msc2);
  k_nms2<<<1, 1024, 0, stream>>>(db2, msc2, out);
}

// Round 16
// 195.369 us; speedup vs baseline: 1.0476x; 1.0476x over previous
//
#include <hip/hip_runtime.h>

#define NB 17340      // 15*34*34
#define TOPK1 3000
#define TOPK2 300
#define PTS 304       // pooledT row stride

__constant__ float c_AW[15] = {9.232984, 16.0, 27.712813, 18.465969, 32.0, 55.425626,
                               36.931937, 64.0, 110.851252, 73.863875, 128.0, 221.702503,
                               147.72775, 256.0, 443.405007};
__constant__ float c_AH[15] = {27.72668, 16.0, 9.237604, 55.453359, 32.0, 18.475209,
                               110.906719, 64.0, 36.950417, 221.813438, 128.0, 73.900834,
                               443.626876, 256.0, 147.801669};

__device__ __forceinline__ unsigned mapf(float f) {
  unsigned u = __float_as_uint(f);
  return (u & 0x80000000u) ? ~u : (u | 0x80000000u);
}
__device__ __forceinline__ float unmapf(unsigned m) {
  unsigned u = (m & 0x80000000u) ? (m & 0x7FFFFFFFu) : ~m;
  return __uint_as_float(u);
}
__device__ __forceinline__ float clipc(float v) {
  return fminf(fmaxf(v, 0.0f), 269.0f);
}
// uniform-lane 64-bit broadcast: SALU v_readlane, NOT ds_bpermute (lane must be uniform)
__device__ __forceinline__ unsigned long long readlane64(unsigned long long v, int lane) {
  unsigned lo = (unsigned)__builtin_amdgcn_readlane((int)(unsigned)v, lane);
  unsigned hi = (unsigned)__builtin_amdgcn_readlane((int)(unsigned)(v >> 32), lane);
  return ((unsigned long long)hi << 32) | lo;
}

// ---------------- Kernel 1: RPN decode + keep filter + global histogram ----------------
__global__ void k_decode(const float* __restrict__ cls, const float* __restrict__ pred,
                         float* __restrict__ boxes, float* __restrict__ scores,
                         unsigned int* __restrict__ hist) {
  int i = blockIdx.x * 256 + threadIdx.x;
  if (i >= NB) return;
  int a = i / 1156;
  int rem = i - a * 1156;
  int y = rem / 34;
  int x = rem - y * 34;
  float fg = cls[(15 + a) * 1156 + rem];
  const float* p = pred + a * 4 * 1156 + rem;
  float t0 = p[0]    * (float)0.12677  + (float)0.000437;
  float t1 = p[1156] * (float)0.095741 + (float)0.002586;
  float t2 = p[2312] * (float)0.3173   + (float)-0.123953;
  float t3 = p[3468] * (float)0.281042 + (float)-0.081469;
  float aw = c_AW[a], ah = c_AH[a];
  float cx = t0 * aw + (float)x * 8.0f;
  float cy = t1 * ah + (float)y * 8.0f;
  float bw = expf(t2) * aw;
  float bh = expf(t3) * ah;
  float x1 = clipc(cx - 0.5f * (bw - 1.0f));
  float y1 = clipc(cy - 0.5f * (bh - 1.0f));
  float x2 = clipc(cx + 0.5f * (bw - 1.0f));
  float y2 = clipc(cy + 0.5f * (bh - 1.0f));
  boxes[i * 4 + 0] = x1;
  boxes[i * 4 + 1] = y1;
  boxes[i * 4 + 2] = x2;
  boxes[i * 4 + 3] = y2;
  float w2 = x2 - x1 + 1.0f, h2 = y2 - y1 + 1.0f;
  bool keep = (fg >= 0.2f) && ((w2 >= (float)6.16056) || (h2 >= (float)6.16056));
  scores[i] = keep ? fg : -1.0f;
  if (keep) atomicAdd(&hist[mapf(fg) >> 18], 1u);
}

// ---------------- Kernel 2a: cutoff bucket (single block) ----------------
__global__ __launch_bounds__(256) void k_cutoff(const unsigned int* __restrict__ hist,
                                                unsigned int* __restrict__ bcut) {
  const int t = threadIdx.x;
  __shared__ unsigned int sh[16384];
  __shared__ unsigned int coarse[256];
  for (int i = t; i < 16384; i += 256) sh[i] = hist[i];
  __syncthreads();
  {
    unsigned s = 0;
    int b0 = t * 64;
    for (int b = 0; b < 64; ++b) s += sh[b0 + b];
    coarse[t] = s;
  }
  __syncthreads();
  if (t == 0) {
    unsigned acc = 0, nbefore = 0;
    int C = 0;
    for (int c = 255; c >= 0; --c) {
      if (acc + coarse[c] >= (unsigned)TOPK1) { C = c; nbefore = acc; break; }
      acc += coarse[c];
    }
    unsigned acc2 = nbefore;
    int B = C * 64;
    for (int b = C * 64 + 63; b >= C * 64; --b) {
      if (acc2 + sh[b] >= (unsigned)TOPK1) { B = b; break; }
      acc2 += sh[b];
    }
    bcut[0] = (unsigned)B;
  }
}

// ---------------- Kernel 2b: parallel compact (no hist staging) ----------------
__global__ __launch_bounds__(256) void k_compact(const float* __restrict__ scores,
                                                 const unsigned int* __restrict__ bcut,
                                                 unsigned int* __restrict__ cnt,
                                                 unsigned long long* __restrict__ keys) {
  int i = blockIdx.x * 256 + threadIdx.x;
  const unsigned B = bcut[0];
  if (i < NB) {
    unsigned m = mapf(scores[i]);
    if ((m >> 18) >= B) {
      unsigned p = atomicAdd(cnt, 1u);
      if (p < 4096u) keys[p] = ((unsigned long long)m << 15) | (unsigned)(32767 - i);
    }
  }
}

// ---------------- Kernel 3: exact rank-by-count sort (128 blocks, 8 lanes/key) ------------
__global__ __launch_bounds__(256) void k_sort(const float* __restrict__ boxes,
                                              const unsigned int* __restrict__ cnt,
                                              const unsigned long long* __restrict__ keys,
                                              unsigned int* __restrict__ sscore,
                                              float4* __restrict__ sbox) {
  const int t = threadIdx.x;
  __shared__ unsigned long long lk[4096];
  const int K = min((int)cnt[0], 4096);
  for (int i = t; i < 4096; i += 256) lk[i] = (i < K) ? keys[i] : 0ull;
  __syncthreads();
  int p = blockIdx.x * 32 + (t >> 3);   // 8 lanes per key, 32 keys per block
  const int s = t & 7;
  if (p < K) {
    unsigned long long kp = lk[p];
    int r = 0;
    for (int q = s; q < 4096; q += 64) {   // 64 fixed iterations
#pragma unroll
      for (int u = 0; u < 8; ++u) r += (lk[q + 8 * u] > kp) ? 1 : 0;
    }
    r += __shfl_xor(r, 1);
    r += __shfl_xor(r, 2);
    r += __shfl_xor(r, 4);
    if (s == 0 && r < TOPK1) {
      int idx = 32767 - (int)(kp & 32767ull);
      sscore[r] = (unsigned)(kp >> 15);
      sbox[r] = ((const float4*)boxes)[idx];
    }
  }
}

// ---------------- Kernel 4: IoU suppression bitmap (all CUs) ----------------
__global__ __launch_bounds__(64) void k_iou(const float4* __restrict__ sbox,
                                            unsigned long long* __restrict__ mat) {
  const int wi = blockIdx.x, wj = blockIdx.y;
  if (wj < wi) return;
  __shared__ float4 cb[64];
  __shared__ float car[64];
  const int l = threadIdx.x;
  float4 c = sbox[wj * 64 + l];
  cb[l] = c;
  car[l] = (c.z - c.x + 1.0f) * (c.w - c.y + 1.0f);
  __syncthreads();
  const int ri = wi * 64 + l;
  float4 r = sbox[ri];
  float rar = (r.z - r.x + 1.0f) * (r.w - r.y + 1.0f);
  unsigned long long m = 0ull;
#pragma unroll 16
  for (int j = 0; j < 64; ++j) {
    float4 cc = cb[j];
    float iw = fmaxf(fminf(r.z, cc.z) - fmaxf(r.x, cc.x) + 1.0f, 0.0f);
    float ih = fmaxf(fminf(r.w, cc.w) - fmaxf(r.y, cc.y) + 1.0f, 0.0f);
    float inter = iw * ih;
    float iou = inter / (car[j] + rar - inter);
    if (iou > 0.7f) m |= (1ull << j);
  }
  mat[ri * 48 + wj] = m;
}

// ---------------- Kernel 5: bitmap greedy NMS-300, uniform-mask + 2-deep speculation ------
// (reverted to the round-12 proven version: best measured, ~33-36 us)
__global__ __launch_bounds__(256) void k_nms1(const unsigned int* __restrict__ sscore,
                                              const float4* __restrict__ sbox,
                                              const unsigned long long* __restrict__ mat,
                                              float* __restrict__ dout,
                                              float* __restrict__ rois_xy,
                                              float* __restrict__ validf) {
  const int t = threadIdx.x;
  __shared__ unsigned long long rowbuf[2][64][48];   // 49152 B
  __shared__ unsigned int sc[3008];
  __shared__ int arank[300];
  __shared__ int s_A;
  for (int i = t; i < 3008; i += 256) sc[i] = (i < TOPK1) ? sscore[i] : 0u;
  if (t == 0) s_A = 0;

  // prologue: all threads stage chunk 0
  {
    unsigned long long r0v[12];
#pragma unroll
    for (int i = 0; i < 12; ++i) r0v[i] = mat[t + 256 * i];
#pragma unroll
    for (int i = 0; i < 12; ++i) {
      int idx = t + 256 * i;
      rowbuf[0][idx / 48][idx % 48] = r0v[i];
    }
  }
  // staging waves pre-issue chunk 1 (rgA: odd chunks) and chunk 2 (rgB: even chunks)
  unsigned long long rgA[16], rgB[16];
  const int st = t - 64;
  if (t >= 64) {
#pragma unroll
    for (int i = 0; i < 16; ++i) rgA[i] = mat[1 * 3072 + st + 192 * i];
#pragma unroll
    for (int i = 0; i < 16; ++i) rgB[i] = mat[2 * 3072 + st + 192 * i];
  }
  __syncthreads();

  unsigned long long run = 0ull;   // wave0: lane w holds running-suppression word w
  int A = 0;
  const int l = t & 63;
  const int lw = (l < 48) ? l : 0;  // clamp for LDS row reads (words 48..63 unused)
  for (int c = 0; c < 47; ++c) {
    if (t < 64) {
      const bool okw = (l >= c) && (l < 47);
      unsigned long long supw = readlane64(run, c);
      bool aliveb = (sc[c * 64 + l] > 0x80000000u) && !((supw >> l) & 1ull);
      unsigned long long alive = __ballot(aliveb);   // wave-uniform alive mask
      int Aw = A;
      const int buf = c & 1;
      while (alive != 0ull && Aw < 300) {
        int j1 = __ffsll((long long)alive) - 1;                  // highest key
        unsigned long long rest = alive & (alive - 1ull);
        int j2 = (rest != 0ull) ? (__ffsll((long long)rest) - 1) : -1;
        unsigned long long v1 = rowbuf[buf][j1][lw];             // accept row
        unsigned long long v2 = rowbuf[buf][(j2 >= 0 ? j2 : j1)][lw];  // speculative
        if (l == 0) arank[Aw] = c * 64 + j1;
        Aw++;
        unsigned long long kill1 = readlane64(v1, c);            // row j1 word c (uniform)
        run |= okw ? v1 : 0ull;
        alive &= ~kill1;                                         // self-bit clears j1
        if (j2 >= 0 && ((alive >> j2) & 1ull) && Aw < 300) {     // speculation hit
          if (l == 0) arank[Aw] = c * 64 + j2;
          Aw++;
          unsigned long long kill2 = readlane64(v2, c);
          run |= okw ? v2 : 0ull;
          alive &= ~kill2;
        }
      }
      A = Aw;
      if (l == 0) s_A = Aw;
    } else if (c < 46) {
      // write chunk c+1; re-issue same register set for chunk c+3
      int nb = (c + 1) & 1;
      if (((c + 1) & 1) == 1) {   // odd chunk -> rgA
#pragma unroll
        for (int i = 0; i < 16; ++i) {
          int idx = st + 192 * i;
          rowbuf[nb][idx / 48][idx % 48] = rgA[i];
        }
        if (c + 3 <= 46) {
#pragma unroll
          for (int i = 0; i < 16; ++i) rgA[i] = mat[(c + 3) * 3072 + st + 192 * i];
        }
      } else {                    // even chunk -> rgB
#pragma unroll
        for (int i = 0; i < 16; ++i) {
          int idx = st + 192 * i;
          rowbuf[nb][idx / 48][idx % 48] = rgB[i];
        }
        if (c + 3 <= 46) {
#pragma unroll
          for (int i = 0; i < 16; ++i) rgB[i] = mat[(c + 3) * 3072 + st + 192 * i];
        }
      }
    }
    __syncthreads();
    A = s_A;
    if (A >= 300) break;
    if (c < 46 && sc[(c + 1) * 64] <= 0x80000000u) break;  // rest invalid
  }
  // parallel write-back
  for (int a = t; a < A; a += 256) {
    int rk = arank[a];
    float4 b = sbox[rk];
    dout[30 + a * 5 + 0] = 0.0f;
    dout[30 + a * 5 + 1] = b.x;
    dout[30 + a * 5 + 2] = b.y;
    dout[30 + a * 5 + 3] = b.z;
    dout[30 + a * 5 + 4] = b.w;
    dout[1530 + a] = unmapf(sc[rk]);
    rois_xy[a * 4 + 0] = b.x; rois_xy[a * 4 + 1] = b.y;
    rois_xy[a * 4 + 2] = b.z; rois_xy[a * 4 + 3] = b.w;
    validf[a] = 1.0f;
  }
  for (int z = 30 + A * 5 + t; z < 1530; z += 256) dout[z] = 0.f;
  for (int z = 1530 + A + t; z < 1830; z += 256) dout[z] = 0.f;
  for (int z = A * 4 + t; z < 1200; z += 256) rois_xy[z] = 0.f;
  for (int z = A + t; z < 300; z += 256) validf[z] = 0.f;
}

// ---------------- Kernel 6: PSROI pooling with hoisted coordinate tables ----------------
__global__ __launch_bounds__(256) void k_psroi(const float* __restrict__ ft,
                                               const float* __restrict__ rois_xy,
                                               float* __restrict__ pooledT) {
  int r = blockIdx.x;
  __shared__ int2 ycs[28];
  __shared__ float2 wys[28];
  __shared__ int2 xcs[28];
  __shared__ float2 wxs[28];
  float r0 = rois_xy[r * 4 + 0], r1 = rois_xy[r * 4 + 1];
  float r2 = rois_xy[r * 4 + 2], r3 = rois_xy[r * 4 + 3];
  float sw = r0 * 0.125f;
  float sh = r1 * 0.125f;
  float ew = (r2 + 1.0f) * 0.125f;
  float eh = (r3 + 1.0f) * 0.125f;
  float rh = fmaxf(eh - sh, 0.1f);
  float rw = fmaxf(ew - sw, 0.1f);
  float bh = rh / 7.0f;
  float bwd = rw / 7.0f;
  const int t = threadIdx.x;
  if (t < 28) {
    int p = t >> 2, sy = t & 3;
    float ys = sh + (float)p * bh + ((float)sy + 0.5f) * (bh * 0.25f);
    float y0f = floorf(ys);
    float dy = ys - y0f;
    int y0 = (int)y0f;
    float wy0 = (1.0f - dy) * ((y0 >= 0 && y0 < 34) ? 1.f : 0.f);
    float wy1 = dy * ((y0 + 1 >= 0 && y0 + 1 < 34) ? 1.f : 0.f);
    ycs[t] = make_int2(min(max(y0, 0), 33), min(max(y0 + 1, 0), 33));
    wys[t] = make_float2(wy0, wy1);
  } else if (t >= 32 && t < 60) {
    int q = (t - 32) >> 2, sx = (t - 32) & 3;
    float xs = sw + (float)q * bwd + ((float)sx + 0.5f) * (bwd * 0.25f);
    float x0f = floorf(xs);
    float dx = xs - x0f;
    int x0 = (int)x0f;
    float wx0 = (1.0f - dx) * ((x0 >= 0 && x0 < 34) ? 1.f : 0.f);
    float wx1 = dx * ((x0 + 1 >= 0 && x0 + 1 < 34) ? 1.f : 0.f);
    xcs[t - 32] = make_int2(min(max(x0, 0), 33), min(max(x0 + 1, 0), 33));
    wxs[t - 32] = make_float2(wx0, wx1);
  }
  __syncthreads();
  for (int o = t; o < 490; o += 256) {
    int pq = o % 49;
    int p = pq / 7, q = pq - p * 7;
    const float* base = ft + o * 1156;
    float acc = 0.f;
#pragma unroll
    for (int sy = 0; sy < 4; ++sy) {
      int2 yc = ycs[p * 4 + sy];
      float2 wy = wys[p * 4 + sy];
#pragma unroll
      for (int sx = 0; sx < 4; ++sx) {
        int2 xc = xcs[q * 4 + sx];
        float2 wx = wxs[q * 4 + sx];
        float v00 = base[yc.x * 34 + xc.x], v01 = base[yc.x * 34 + xc.y];
        float v10 = base[yc.y * 34 + xc.x], v11 = base[yc.y * 34 + xc.y];
        acc += wy.x * wx.x * v00 + wy.x * wx.y * v01 + wy.y * wx.x * v10 + wy.y * wx.y * v11;
      }
    }
    pooledT[o * PTS + r] = acc * (1.0f / 16.0f);
  }
}

// ---------------- Kernel 7: FC1 GEMM 64x32 tiles (320 blocks), 1 barrier/step -------------
__global__ __launch_bounds__(256) void k_fc1(const float* __restrict__ pooledT,
                                             const float* __restrict__ Wi,
                                             const float* __restrict__ bi,
                                             float* __restrict__ feat) {
  __shared__ float As[2][32][68];
  __shared__ float Bs[2][32][36];   // [kk][oo], pad 36
  const int t = threadIdx.x;
  const int tr = t >> 4, tc = t & 15;          // 16x16 thread grid
  const int b = blockIdx.x;
  const int xcd = b & 7, s = b >> 3;
  const int r0 = (s % 5) * 64;                 // roi tile
  const int o0 = (xcd + 8 * (s / 5)) * 32;     // out tile of 32 cols
  float acc[4][2];
#pragma unroll
  for (int i = 0; i < 4; ++i) { acc[i][0] = 0.f; acc[i][1] = 0.f; }
  float ra[8], rb[4];

#pragma unroll
  for (int i = 0; i < 8; ++i) {
    int idx = t + 256 * i;
    int kk = idx >> 6, rr = idx & 63;
    ra[i] = (kk < 490 && r0 + rr < 300) ? pooledT[kk * PTS + r0 + rr] : 0.f;
  }
#pragma unroll
  for (int i = 0; i < 4; ++i) {
    int idx = t + 256 * i;
    int oo = idx >> 5, k2 = idx & 31;
    rb[i] = Wi[(o0 + oo) * 490 + k2];
  }
#pragma unroll
  for (int i = 0; i < 8; ++i) {
    int idx = t + 256 * i;
    As[0][idx >> 6][idx & 63] = ra[i];
  }
#pragma unroll
  for (int i = 0; i < 4; ++i) {
    int idx = t + 256 * i;
    Bs[0][idx & 31][idx >> 5] = rb[i];         // [kk][oo]
  }
  __syncthreads();

  int cur = 0;
  for (int step = 0; step < 16; ++step) {
    if (step < 15) {
      int k0n = (step + 1) * 32;
#pragma unroll
      for (int i = 0; i < 8; ++i) {
        int idx = t + 256 * i;
        int kk = idx >> 6, rr = idx & 63;
        int k = k0n + kk;
        ra[i] = (k < 490 && r0 + rr < 300) ? pooledT[k * PTS + r0 + rr] : 0.f;
      }
#pragma unroll
      for (int i = 0; i < 4; ++i) {
        int idx = t + 256 * i;
        int oo = idx >> 5, k2 = k0n + (idx & 31);
        rb[i] = (k2 < 490) ? Wi[(o0 + oo) * 490 + k2] : 0.f;
      }
    }
#pragma unroll
    for (int kk = 0; kk < 32; ++kk) {
      float4 a4 = *(const float4*)&As[cur][kk][tr * 4];
      float2 b2 = *(const float2*)&Bs[cur][kk][tc * 2];
      acc[0][0] += a4.x * b2.x; acc[0][1] += a4.x * b2.y;
      acc[1][0] += a4.y * b2.x; acc[1][1] += a4.y * b2.y;
      acc[2][0] += a4.z * b2.x; acc[2][1] += a4.z * b2.y;
      acc[3][0] += a4.w * b2.x; acc[3][1] += a4.w * b2.y;
    }
    if (step < 15) {
      int nxt = cur ^ 1;
#pragma unroll
      for (int i = 0; i < 8; ++i) {
        int idx = t + 256 * i;
        As[nxt][idx >> 6][idx & 63] = ra[i];
      }
#pragma unroll
      for (int i = 0; i < 4; ++i) {
        int idx = t + 256 * i;
        Bs[nxt][idx & 31][idx >> 5] = rb[i];
      }
      cur = nxt;
    }
    __syncthreads();   // single barrier per step (writes to nxt can't alias reads of cur)
  }
  float2 bias = *(const float2*)&bi[o0 + tc * 2];
#pragma unroll
  for (int i = 0; i < 4; ++i) {
    int r = r0 + tr * 4 + i;
    if (r < 300) {
      float2 v;
      v.x = fmaxf(acc[i][0] + bias.x, 0.f);
      v.y = fmaxf(acc[i][1] + bias.y, 0.f);
      *(float2*)&feat[r * 2048 + o0 + tc * 2] = v;
    }
  }
}

// ---------------- Kernel 8: FC2 heads + softmax + per-class decode (fused) ----------------
__global__ __launch_bounds__(256) void k_fc2(const float* __restrict__ feat,
                                             const float* __restrict__ Wc,
                                             const float* __restrict__ bc,
                                             const float* __restrict__ Wb,
                                             const float* __restrict__ bb,
                                             const float* __restrict__ rois_xy,
                                             const float* __restrict__ validf,
                                             float* __restrict__ db2,
                                             float* __restrict__ msc2) {
  int r = blockIdx.x;
  int t = threadIdx.x;
  int l = t & 63, w = t >> 6;
  __shared__ float frow[2048];
  __shared__ float s_logit[20];
  __shared__ float s_probs[4];
  for (int i = t; i < 512; i += 256)
    ((float4*)frow)[i] = ((const float4*)(feat + r * 2048))[i];
  __syncthreads();
  for (int o = w; o < 20; o += 4) {
    const float* wr = (o < 4) ? (Wc + o * 2048) : (Wb + (o - 4) * 2048);
    float p = 0.f;
#pragma unroll
    for (int j = 0; j < 8; ++j) {
      float4 wv = ((const float4*)wr)[l + 64 * j];
      float4 fv = ((const float4*)frow)[l + 64 * j];
      p += wv.x * fv.x + wv.y * fv.y + wv.z * fv.z + wv.w * fv.w;
    }
    for (int off = 32; off > 0; off >>= 1) p += __shfl_xor(p, off);
    if (l == 0) s_logit[o] = p + ((o < 4) ? bc[o] : bb[o - 4]);
  }
  __syncthreads();
  if (t == 0) {
    float m = fmaxf(fmaxf(s_logit[0], s_logit[1]), fmaxf(s_logit[2], s_logit[3]));
    float e0 = expf(s_logit[0] - m), e1 = expf(s_logit[1] - m);
    float e2 = expf(s_logit[2] - m), e3 = expf(s_logit[3] - m);
    float ssum = e0 + e1 + e2 + e3;
    s_probs[0] = e0 / ssum; s_probs[1] = e1 / ssum;
    s_probs[2] = e2 / ssum; s_probs[3] = e3 / ssum;
  }
  __syncthreads();
  if (t < 3) {
    int c = t + 1;
    float x1 = rois_xy[r * 4 + 0], y1 = rois_xy[r * 4 + 1];
    float x2 = rois_xy[r * 4 + 2], y2 = rois_xy[r * 4 + 3];
    float rwv = x2 - x1 + 1.0f, rhv = y2 - y1 + 1.0f;
    float rcx = x1 + 0.5f * (rwv - 1.0f), rcy = y1 + 0.5f * (rhv - 1.0f);
    float t0 = s_logit[4 + 4 * c + 0] * 0.1f;
    float t1 = s_logit[4 + 4 * c + 1] * 0.1f;
    float t2 = s_logit[4 + 4 * c + 2] * 0.2f;
    float t3 = s_logit[4 + 4 * c + 3] * 0.2f;
    float cx = t0 * rwv + rcx, cy = t1 * rhv + rcy;
    float bw = expf(t2) * rwv, bh = expf(t3) * rhv;
    float dx1 = clipc(cx - 0.5f * (bw - 1.0f));
    float dy1 = clipc(cy - 0.5f * (bh - 1.0f));
    float dx2 = clipc(cx + 0.5f * (bw - 1.0f));
    float dy2 = clipc(cy + 0.5f * (bh - 1.0f));
    float dw = dx2 - dx1 + 1.0f, dh = dy2 - dy1 + 1.0f;
    float sc = s_probs[c];
    bool objok = (1.0f - s_probs[0]) >= 0.1f;
    bool valid = validf[r] > 0.5f;
    bool kf = valid && objok && (sc >= 0.1f) && ((dw >= (float)8.8008) || (dh >= (float)8.8008));
    int i2 = (c - 1) * 300 + r;
    db2[i2 * 4 + 0] = dx1; db2[i2 * 4 + 1] = dy1;
    db2[i2 * 4 + 2] = dx2; db2[i2 * 4 + 3] = dy2;
    msc2[i2] = kf ? sc : -1.0f;
  }
}

// ---------------- Kernel 9: rank-sort 900 (padded, unrolled) + greedy NMS-5 ----------------
__global__ __launch_bounds__(1024) void k_nms2(const float* __restrict__ db2,
                                               const float* __restrict__ msc2,
                                               float* __restrict__ dout) {
  const int t = threadIdx.x;
  __shared__ unsigned long long lk[1024];
  __shared__ unsigned long long sk[1024];
  __shared__ float4 abox[5];
  __shared__ float aar[5];
  __shared__ int s_A;
  sk[t] = 0ull;
  lk[t] = (t < 900) ? (((unsigned long long)mapf(msc2[t]) << 10) | (unsigned)(1023 - t)) : 0ull;
  if (t == 0) s_A = 0;
  __syncthreads();
  if (t < 900) {
    unsigned long long kp = lk[t];
    int r = 0;
#pragma unroll 8
    for (int q = 0; q < 1024; ++q) r += (lk[q] > kp) ? 1 : 0;   // zero pads contribute 0
    sk[r] = kp;   // keys unique -> ranks unique
  }
  __syncthreads();
  if (t < 64) {
    int A = 0;
    for (int base = 0; base < TOPK2 && A < 5; base += 64) {
      unsigned headm = (unsigned)(sk[base] >> 10);
      if (headm <= 0x80000000u) break;
      int rank = base + t;
      unsigned long long key = sk[rank];
      unsigned mk = (unsigned)(key >> 10);
      bool active = (rank < TOPK2) && (mk > 0x80000000u);
      int idx = 1023 - (int)(key & 1023ull);
      float4 bx = make_float4(0.f, 0.f, 0.f, 0.f);
      float area = 0.f;
      if (active) {
        bx = ((const float4*)db2)[idx];
        area = (bx.z - bx.x + 1.0f) * (bx.w - bx.y + 1.0f);
      }
      bool alive = active;
      for (int a = 0; a < A; ++a) {
        float4 ab = abox[a];
        float iw = fmaxf(fminf(bx.z, ab.z) - fmaxf(bx.x, ab.x) + 1.0f, 0.0f);
        float ih = fmaxf(fminf(bx.w, ab.w) - fmaxf(bx.y, ab.y) + 1.0f, 0.0f);
        float inter = iw * ih;
        float iou = inter / (area + aar[a] - inter);
        if (iou > 0.5f) { alive = false; break; }
      }
      unsigned long long bal = __ballot(alive);
      while (bal != 0ull && A < 5) {
        int j = __ffsll((long long)bal) - 1;
        float jx1 = __shfl(bx.x, j), jy1 = __shfl(bx.y, j);
        float jx2 = __shfl(bx.z, j), jy2 = __shfl(bx.w, j);
        float jar = __shfl(area, j);
        if (t == j) {
          abox[A] = bx; aar[A] = area;
          dout[A * 6 + 0] = bx.x; dout[A * 6 + 1] = bx.y;
          dout[A * 6 + 2] = bx.z; dout[A * 6 + 3] = bx.w;
          dout[A * 6 + 4] = unmapf(mk);
          dout[A * 6 + 5] = (float)(idx / 300 + 1);
        }
        if (alive) {
          float iw = fmaxf(fminf(bx.z, jx2) - fmaxf(bx.x, jx1) + 1.0f, 0.0f);
          float ih = fmaxf(fminf(bx.w, jy2) - fmaxf(bx.y, jy1) + 1.0f, 0.0f);
          float inter = iw * ih;
          float iou = inter / (area + jar - inter);
          if (iou > 0.5f || t == j) alive = false;
        }
        A++;
        bal = __ballot(alive);
      }
    }
    if (t == 0) s_A = A;
  }
  __syncthreads();
  int A = s_A;
  for (int z = A * 6 + t; z < 30; z += 1024) dout[z] = 0.f;
}

extern "C" void kernel_launch(void* const* d_in, const int* in_sizes, int n_in,
                              void* d_out, int out_size, void* d_ws, size_t ws_size,
                              hipStream_t stream) {
  const float* cls  = (const float*)d_in[0];
  const float* pred = (const float*)d_in[1];
  const float* ft   = (const float*)d_in[2];
  const float* Wi   = (const float*)d_in[3];
  const float* bi   = (const float*)d_in[4];
  const float* Wc   = (const float*)d_in[5];
  const float* bc   = (const float*)d_in[6];
  const float* Wb   = (const float*)d_in[7];
  const float* bb   = (const float*)d_in[8];
  float* out = (float*)d_out;
  float* w = (float*)d_ws;
  // layout (float offsets)
  float* boxes   = w;                                   // 0      .. 69360
  float* scores  = w + 69360;                           // 69360  .. 86700
  unsigned int* hist = (unsigned int*)(w + 86700);      // 86700  .. 103084
  unsigned int* cnt  = (unsigned int*)(w + 103084);     // 103084
  unsigned int* bcut = (unsigned int*)(w + 103085);     // 103085 (written by k_cutoff)
  unsigned long long* keys = (unsigned long long*)(w + 103088); // 4096 u64 -> 111280
  unsigned int* sscore = (unsigned int*)(w + 111280);   // 3000 u32 -> 114280
  float4* sbox   = (float4*)(w + 114280);               // 3008 f4 (padded) -> 126312
  float* rois_xy = w + 126312;                          // .. 127512
  float* validf  = w + 127512;                          // .. 127812
  float* pooledT = w + 127812;                          // 490*304=148960 -> 276772
  float* feat    = w + 276772;                          // 300*2048 -> 891172 (16B aligned)
  unsigned long long* mat = (unsigned long long*)(w + 276772); // aliases feat: 3008*48 u64
  float* db2     = w + 891172;                          // .. 894772 (16B aligned)
  float* msc2    = w + 894772;                          // .. 895672 (~3.58 MB)

  hipMemsetAsync(hist, 0, 16385 * sizeof(unsigned int), stream);  // hist + cnt
  k_decode<<<68, 256, 0, stream>>>(cls, pred, boxes, scores, hist);
  k_cutoff<<<1, 256, 0, stream>>>(hist, bcut);
  k_compact<<<68, 256, 0, stream>>>(scores, bcut, cnt, keys);
  k_sort<<<128, 256, 0, stream>>>(boxes, cnt, keys, sscore, sbox);
  k_iou<<<dim3(47, 47), 64, 0, stream>>>(sbox, mat);
  k_nms1<<<1, 256, 0, stream>>>(sscore, sbox, mat, out, rois_xy, validf);
  k_psroi<<<300, 256, 0, stream>>>(ft, rois_xy, pooledT);
  k_fc1<<<320, 256, 0, stream>>>(pooledT, Wi, bi, feat);
  k_fc2<<<300, 256, 0, stream>>>(feat, Wc, bc, Wb, bb, rois_xy, validf, db2, msc2);
  k_nms2<<<1, 1024, 0, stream>>>(db2, msc2, out);
}

// Round 17
// 191.261 us; speedup vs baseline: 1.0701x; 1.0215x over previous
//
#include <hip/hip_runtime.h>

#define NB 17340      // 15*34*34
#define TOPK1 3000
#define TOPK2 300
#define PTS 304       // pooledT row stride

__constant__ float c_AW[15] = {9.232984, 16.0, 27.712813, 18.465969, 32.0, 55.425626,
                               36.931937, 64.0, 110.851252, 73.863875, 128.0, 221.702503,
                               147.72775, 256.0, 443.405007};
__constant__ float c_AH[15] = {27.72668, 16.0, 9.237604, 55.453359, 32.0, 18.475209,
                               110.906719, 64.0, 36.950417, 221.813438, 128.0, 73.900834,
                               443.626876, 256.0, 147.801669};

__device__ __forceinline__ unsigned mapf(float f) {
  unsigned u = __float_as_uint(f);
  return (u & 0x80000000u) ? ~u : (u | 0x80000000u);
}
__device__ __forceinline__ float unmapf(unsigned m) {
  unsigned u = (m & 0x80000000u) ? (m & 0x7FFFFFFFu) : ~m;
  return __uint_as_float(u);
}
__device__ __forceinline__ float clipc(float v) {
  return fminf(fmaxf(v, 0.0f), 269.0f);
}
// uniform-lane 64-bit broadcast: SALU v_readlane, NOT ds_bpermute (lane must be uniform)
__device__ __forceinline__ unsigned long long readlane64(unsigned long long v, int lane) {
  unsigned lo = (unsigned)__builtin_amdgcn_readlane((int)(unsigned)v, lane);
  unsigned hi = (unsigned)__builtin_amdgcn_readlane((int)(unsigned)(v >> 32), lane);
  return ((unsigned long long)hi << 32) | lo;
}

// ---------------- Kernel 0: zero hist + cnt (replaces 38us runtime fill) ----------------
__global__ __launch_bounds__(256) void k_zero(unsigned int* __restrict__ hist) {
  int i = blockIdx.x * 256 + threadIdx.x;
  if (i < 16385) hist[i] = 0u;   // 16384 hist buckets + cnt (adjacent)
}

// ---------------- Kernel 1: RPN decode + keep filter + global histogram ----------------
__global__ void k_decode(const float* __restrict__ cls, const float* __restrict__ pred,
                         float* __restrict__ boxes, float* __restrict__ scores,
                         unsigned int* __restrict__ hist) {
  int i = blockIdx.x * 256 + threadIdx.x;
  if (i >= NB) return;
  int a = i / 1156;
  int rem = i - a * 1156;
  int y = rem / 34;
  int x = rem - y * 34;
  float fg = cls[(15 + a) * 1156 + rem];
  const float* p = pred + a * 4 * 1156 + rem;
  float t0 = p[0]    * (float)0.12677  + (float)0.000437;
  float t1 = p[1156] * (float)0.095741 + (float)0.002586;
  float t2 = p[2312] * (float)0.3173   + (float)-0.123953;
  float t3 = p[3468] * (float)0.281042 + (float)-0.081469;
  float aw = c_AW[a], ah = c_AH[a];
  float cx = t0 * aw + (float)x * 8.0f;
  float cy = t1 * ah + (float)y * 8.0f;
  float bw = expf(t2) * aw;
  float bh = expf(t3) * ah;
  float x1 = clipc(cx - 0.5f * (bw - 1.0f));
  float y1 = clipc(cy - 0.5f * (bh - 1.0f));
  float x2 = clipc(cx + 0.5f * (bw - 1.0f));
  float y2 = clipc(cy + 0.5f * (bh - 1.0f));
  boxes[i * 4 + 0] = x1;
  boxes[i * 4 + 1] = y1;
  boxes[i * 4 + 2] = x2;
  boxes[i * 4 + 3] = y2;
  float w2 = x2 - x1 + 1.0f, h2 = y2 - y1 + 1.0f;
  bool keep = (fg >= 0.2f) && ((w2 >= (float)6.16056) || (h2 >= (float)6.16056));
  scores[i] = keep ? fg : -1.0f;
  if (keep) atomicAdd(&hist[mapf(fg) >> 18], 1u);
}

// ---------------- Kernel 2a: cutoff bucket (single block) ----------------
__global__ __launch_bounds__(256) void k_cutoff(const unsigned int* __restrict__ hist,
                                                unsigned int* __restrict__ bcut) {
  const int t = threadIdx.x;
  __shared__ unsigned int sh[16384];
  __shared__ unsigned int coarse[256];
  for (int i = t; i < 16384; i += 256) sh[i] = hist[i];
  __syncthreads();
  {
    unsigned s = 0;
    int b0 = t * 64;
    for (int b = 0; b < 64; ++b) s += sh[b0 + b];
    coarse[t] = s;
  }
  __syncthreads();
  if (t == 0) {
    unsigned acc = 0, nbefore = 0;
    int C = 0;
    for (int c = 255; c >= 0; --c) {
      if (acc + coarse[c] >= (unsigned)TOPK1) { C = c; nbefore = acc; break; }
      acc += coarse[c];
    }
    unsigned acc2 = nbefore;
    int B = C * 64;
    for (int b = C * 64 + 63; b >= C * 64; --b) {
      if (acc2 + sh[b] >= (unsigned)TOPK1) { B = b; break; }
      acc2 += sh[b];
    }
    bcut[0] = (unsigned)B;
  }
}

// ---------------- Kernel 2b: parallel compact (no hist staging) ----------------
__global__ __launch_bounds__(256) void k_compact(const float* __restrict__ scores,
                                                 const unsigned int* __restrict__ bcut,
                                                 unsigned int* __restrict__ cnt,
                                                 unsigned long long* __restrict__ keys) {
  int i = blockIdx.x * 256 + threadIdx.x;
  const unsigned B = bcut[0];
  if (i < NB) {
    unsigned m = mapf(scores[i]);
    if ((m >> 18) >= B) {
      unsigned p = atomicAdd(cnt, 1u);
      if (p < 4096u) keys[p] = ((unsigned long long)m << 15) | (unsigned)(32767 - i);
    }
  }
}

// ---------------- Kernel 3: exact rank-by-count sort (128 blocks, 8 lanes/key) ------------
__global__ __launch_bounds__(256) void k_sort(const float* __restrict__ boxes,
                                              const unsigned int* __restrict__ cnt,
                                              const unsigned long long* __restrict__ keys,
                                              unsigned int* __restrict__ sscore,
                                              float4* __restrict__ sbox) {
  const int t = threadIdx.x;
  __shared__ unsigned long long lk[4096];
  const int K = min((int)cnt[0], 4096);
  for (int i = t; i < 4096; i += 256) lk[i] = (i < K) ? keys[i] : 0ull;
  __syncthreads();
  int p = blockIdx.x * 32 + (t >> 3);   // 8 lanes per key, 32 keys per block
  const int s = t & 7;
  if (p < K) {
    unsigned long long kp = lk[p];
    int r = 0;
    for (int q = s; q < 4096; q += 64) {   // 64 fixed iterations
#pragma unroll
      for (int u = 0; u < 8; ++u) r += (lk[q + 8 * u] > kp) ? 1 : 0;
    }
    r += __shfl_xor(r, 1);
    r += __shfl_xor(r, 2);
    r += __shfl_xor(r, 4);
    if (s == 0 && r < TOPK1) {
      int idx = 32767 - (int)(kp & 32767ull);
      sscore[r] = (unsigned)(kp >> 15);
      sbox[r] = ((const float4*)boxes)[idx];
    }
  }
}

// ---------------- Kernel 4: IoU suppression bitmap (all CUs) ----------------
__global__ __launch_bounds__(64) void k_iou(const float4* __restrict__ sbox,
                                            unsigned long long* __restrict__ mat) {
  const int wi = blockIdx.x, wj = blockIdx.y;
  if (wj < wi) return;
  __shared__ float4 cb[64];
  __shared__ float car[64];
  const int l = threadIdx.x;
  float4 c = sbox[wj * 64 + l];
  cb[l] = c;
  car[l] = (c.z - c.x + 1.0f) * (c.w - c.y + 1.0f);
  __syncthreads();
  const int ri = wi * 64 + l;
  float4 r = sbox[ri];
  float rar = (r.z - r.x + 1.0f) * (r.w - r.y + 1.0f);
  unsigned long long m = 0ull;
#pragma unroll 16
  for (int j = 0; j < 64; ++j) {
    float4 cc = cb[j];
    float iw = fmaxf(fminf(r.z, cc.z) - fmaxf(r.x, cc.x) + 1.0f, 0.0f);
    float ih = fmaxf(fminf(r.w, cc.w) - fmaxf(r.y, cc.y) + 1.0f, 0.0f);
    float inter = iw * ih;
    float iou = inter / (car[j] + rar - inter);
    if (iou > 0.7f) m |= (1ull << j);
  }
  mat[ri * 48 + wj] = m;
}

// ---------------- Kernel 5: bitmap greedy NMS-300, uniform-mask + 2-deep speculation ------
__global__ __launch_bounds__(256) void k_nms1(const unsigned int* __restrict__ sscore,
                                              const float4* __restrict__ sbox,
                                              const unsigned long long* __restrict__ mat,
                                              float* __restrict__ dout,
                                              float* __restrict__ rois_xy,
                                              float* __restrict__ validf) {
  const int t = threadIdx.x;
  __shared__ unsigned long long rowbuf[2][64][48];   // 49152 B
  __shared__ unsigned int sc[3008];
  __shared__ int arank[300];
  __shared__ int s_A;
  for (int i = t; i < 3008; i += 256) sc[i] = (i < TOPK1) ? sscore[i] : 0u;
  if (t == 0) s_A = 0;

  // prologue: all threads stage chunk 0
  {
    unsigned long long r0v[12];
#pragma unroll
    for (int i = 0; i < 12; ++i) r0v[i] = mat[t + 256 * i];
#pragma unroll
    for (int i = 0; i < 12; ++i) {
      int idx = t + 256 * i;
      rowbuf[0][idx / 48][idx % 48] = r0v[i];
    }
  }
  // staging waves pre-issue chunk 1 (rgA: odd chunks) and chunk 2 (rgB: even chunks)
  unsigned long long rgA[16], rgB[16];
  const int st = t - 64;
  if (t >= 64) {
#pragma unroll
    for (int i = 0; i < 16; ++i) rgA[i] = mat[1 * 3072 + st + 192 * i];
#pragma unroll
    for (int i = 0; i < 16; ++i) rgB[i] = mat[2 * 3072 + st + 192 * i];
  }
  __syncthreads();

  unsigned long long run = 0ull;   // wave0: lane w holds running-suppression word w
  int A = 0;
  const int l = t & 63;
  const int lw = (l < 48) ? l : 0;  // clamp for LDS row reads (words 48..63 unused)
  for (int c = 0; c < 47; ++c) {
    if (t < 64) {
      const bool okw = (l >= c) && (l < 47);
      unsigned long long supw = readlane64(run, c);
      bool aliveb = (sc[c * 64 + l] > 0x80000000u) && !((supw >> l) & 1ull);
      unsigned long long alive = __ballot(aliveb);   // wave-uniform alive mask
      int Aw = A;
      const int buf = c & 1;
      while (alive != 0ull && Aw < 300) {
        int j1 = __ffsll((long long)alive) - 1;                  // highest key
        unsigned long long rest = alive & (alive - 1ull);
        int j2 = (rest != 0ull) ? (__ffsll((long long)rest) - 1) : -1;
        unsigned long long v1 = rowbuf[buf][j1][lw];             // accept row
        unsigned long long v2 = rowbuf[buf][(j2 >= 0 ? j2 : j1)][lw];  // speculative
        if (l == 0) arank[Aw] = c * 64 + j1;
        Aw++;
        unsigned long long kill1 = readlane64(v1, c);            // row j1 word c (uniform)
        run |= okw ? v1 : 0ull;
        alive &= ~kill1;                                         // self-bit clears j1
        if (j2 >= 0 && ((alive >> j2) & 1ull) && Aw < 300) {     // speculation hit
          if (l == 0) arank[Aw] = c * 64 + j2;
          Aw++;
          unsigned long long kill2 = readlane64(v2, c);
          run |= okw ? v2 : 0ull;
          alive &= ~kill2;
        }
      }
      A = Aw;
      if (l == 0) s_A = Aw;
    } else if (c < 46) {
      // write chunk c+1; re-issue same register set for chunk c+3
      int nb = (c + 1) & 1;
      if (((c + 1) & 1) == 1) {   // odd chunk -> rgA
#pragma unroll
        for (int i = 0; i < 16; ++i) {
          int idx = st + 192 * i;
          rowbuf[nb][idx / 48][idx % 48] = rgA[i];
        }
        if (c + 3 <= 46) {
#pragma unroll
          for (int i = 0; i < 16; ++i) rgA[i] = mat[(c + 3) * 3072 + st + 192 * i];
        }
      } else {                    // even chunk -> rgB
#pragma unroll
        for (int i = 0; i < 16; ++i) {
          int idx = st + 192 * i;
          rowbuf[nb][idx / 48][idx % 48] = rgB[i];
        }
        if (c + 3 <= 46) {
#pragma unroll
          for (int i = 0; i < 16; ++i) rgB[i] = mat[(c + 3) * 3072 + st + 192 * i];
        }
      }
    }
    __syncthreads();
    A = s_A;
    if (A >= 300) break;
    if (c < 46 && sc[(c + 1) * 64] <= 0x80000000u) break;  // rest invalid
  }
  // parallel write-back
  for (int a = t; a < A; a += 256) {
    int rk = arank[a];
    float4 b = sbox[rk];
    dout[30 + a * 5 + 0] = 0.0f;
    dout[30 + a * 5 + 1] = b.x;
    dout[30 + a * 5 + 2] = b.y;
    dout[30 + a * 5 + 3] = b.z;
    dout[30 + a * 5 + 4] = b.w;
    dout[1530 + a] = unmapf(sc[rk]);
    rois_xy[a * 4 + 0] = b.x; rois_xy[a * 4 + 1] = b.y;
    rois_xy[a * 4 + 2] = b.z; rois_xy[a * 4 + 3] = b.w;
    validf[a] = 1.0f;
  }
  for (int z = 30 + A * 5 + t; z < 1530; z += 256) dout[z] = 0.f;
  for (int z = 1530 + A + t; z < 1830; z += 256) dout[z] = 0.f;
  for (int z = A * 4 + t; z < 1200; z += 256) rois_xy[z] = 0.f;
  for (int z = A + t; z < 300; z += 256) validf[z] = 0.f;
}

// ---------------- Kernel 6: PSROI pooling with hoisted coordinate tables ----------------
__global__ __launch_bounds__(256) void k_psroi(const float* __restrict__ ft,
                                               const float* __restrict__ rois_xy,
                                               float* __restrict__ pooledT) {
  int r = blockIdx.x;
  __shared__ int2 ycs[28];
  __shared__ float2 wys[28];
  __shared__ int2 xcs[28];
  __shared__ float2 wxs[28];
  float r0 = rois_xy[r * 4 + 0], r1 = rois_xy[r * 4 + 1];
  float r2 = rois_xy[r * 4 + 2], r3 = rois_xy[r * 4 + 3];
  float sw = r0 * 0.125f;
  float sh = r1 * 0.125f;
  float ew = (r2 + 1.0f) * 0.125f;
  float eh = (r3 + 1.0f) * 0.125f;
  float rh = fmaxf(eh - sh, 0.1f);
  float rw = fmaxf(ew - sw, 0.1f);
  float bh = rh / 7.0f;
  float bwd = rw / 7.0f;
  const int t = threadIdx.x;
  if (t < 28) {
    int p = t >> 2, sy = t & 3;
    float ys = sh + (float)p * bh + ((float)sy + 0.5f) * (bh * 0.25f);
    float y0f = floorf(ys);
    float dy = ys - y0f;
    int y0 = (int)y0f;
    float wy0 = (1.0f - dy) * ((y0 >= 0 && y0 < 34) ? 1.f : 0.f);
    float wy1 = dy * ((y0 + 1 >= 0 && y0 + 1 < 34) ? 1.f : 0.f);
    ycs[t] = make_int2(min(max(y0, 0), 33), min(max(y0 + 1, 0), 33));
    wys[t] = make_float2(wy0, wy1);
  } else if (t >= 32 && t < 60) {
    int q = (t - 32) >> 2, sx = (t - 32) & 3;
    float xs = sw + (float)q * bwd + ((float)sx + 0.5f) * (bwd * 0.25f);
    float x0f = floorf(xs);
    float dx = xs - x0f;
    int x0 = (int)x0f;
    float wx0 = (1.0f - dx) * ((x0 >= 0 && x0 < 34) ? 1.f : 0.f);
    float wx1 = dx * ((x0 + 1 >= 0 && x0 + 1 < 34) ? 1.f : 0.f);
    xcs[t - 32] = make_int2(min(max(x0, 0), 33), min(max(x0 + 1, 0), 33));
    wxs[t - 32] = make_float2(wx0, wx1);
  }
  __syncthreads();
  for (int o = t; o < 490; o += 256) {
    int pq = o % 49;
    int p = pq / 7, q = pq - p * 7;
    const float* base = ft + o * 1156;
    float acc = 0.f;
#pragma unroll
    for (int sy = 0; sy < 4; ++sy) {
      int2 yc = ycs[p * 4 + sy];
      float2 wy = wys[p * 4 + sy];
#pragma unroll
      for (int sx = 0; sx < 4; ++sx) {
        int2 xc = xcs[q * 4 + sx];
        float2 wx = wxs[q * 4 + sx];
        float v00 = base[yc.x * 34 + xc.x], v01 = base[yc.x * 34 + xc.y];
        float v10 = base[yc.y * 34 + xc.x], v11 = base[yc.y * 34 + xc.y];
        acc += wy.x * wx.x * v00 + wy.x * wx.y * v01 + wy.y * wx.x * v10 + wy.y * wx.y * v11;
      }
    }
    pooledT[o * PTS + r] = acc * (1.0f / 16.0f);
  }
}

// ---------------- Kernel 7: FC1 GEMM 64x32 tiles (320 blocks), 1 barrier/step -------------
__global__ __launch_bounds__(256) void k_fc1(const float* __restrict__ pooledT,
                                             const float* __restrict__ Wi,
                                             const float* __restrict__ bi,
                                             float* __restrict__ feat) {
  __shared__ float As[2][32][68];
  __shared__ float Bs[2][32][36];   // [kk][oo], pad 36
  const int t = threadIdx.x;
  const int tr = t >> 4, tc = t & 15;          // 16x16 thread grid
  const int b = blockIdx.x;
  const int xcd = b & 7, s = b >> 3;
  const int r0 = (s % 5) * 64;                 // roi tile
  const int o0 = (xcd + 8 * (s / 5)) * 32;     // out tile of 32 cols
  float acc[4][2];
#pragma unroll
  for (int i = 0; i < 4; ++i) { acc[i][0] = 0.f; acc[i][1] = 0.f; }
  float ra[8], rb[4];

#pragma unroll
  for (int i = 0; i < 8; ++i) {
    int idx = t + 256 * i;
    int kk = idx >> 6, rr = idx & 63;
    ra[i] = (kk < 490 && r0 + rr < 300) ? pooledT[kk * PTS + r0 + rr] : 0.f;
  }
#pragma unroll
  for (int i = 0; i < 4; ++i) {
    int idx = t + 256 * i;
    int oo = idx >> 5, k2 = idx & 31;
    rb[i] = Wi[(o0 + oo) * 490 + k2];
  }
#pragma unroll
  for (int i = 0; i < 8; ++i) {
    int idx = t + 256 * i;
    As[0][idx >> 6][idx & 63] = ra[i];
  }
#pragma unroll
  for (int i = 0; i < 4; ++i) {
    int idx = t + 256 * i;
    Bs[0][idx & 31][idx >> 5] = rb[i];         // [kk][oo]
  }
  __syncthreads();

  int cur = 0;
  for (int step = 0; step < 16; ++step) {
    if (step < 15) {
      int k0n = (step + 1) * 32;
#pragma unroll
      for (int i = 0; i < 8; ++i) {
        int idx = t + 256 * i;
        int kk = idx >> 6, rr = idx & 63;
        int k = k0n + kk;
        ra[i] = (k < 490 && r0 + rr < 300) ? pooledT[k * PTS + r0 + rr] : 0.f;
      }
#pragma unroll
      for (int i = 0; i < 4; ++i) {
        int idx = t + 256 * i;
        int oo = idx >> 5, k2 = k0n + (idx & 31);
        rb[i] = (k2 < 490) ? Wi[(o0 + oo) * 490 + k2] : 0.f;
      }
    }
#pragma unroll
    for (int kk = 0; kk < 32; ++kk) {
      float4 a4 = *(const float4*)&As[cur][kk][tr * 4];
      float2 b2 = *(const float2*)&Bs[cur][kk][tc * 2];
      acc[0][0] += a4.x * b2.x; acc[0][1] += a4.x * b2.y;
      acc[1][0] += a4.y * b2.x; acc[1][1] += a4.y * b2.y;
      acc[2][0] += a4.z * b2.x; acc[2][1] += a4.z * b2.y;
      acc[3][0] += a4.w * b2.x; acc[3][1] += a4.w * b2.y;
    }
    if (step < 15) {
      int nxt = cur ^ 1;
#pragma unroll
      for (int i = 0; i < 8; ++i) {
        int idx = t + 256 * i;
        As[nxt][idx >> 6][idx & 63] = ra[i];
      }
#pragma unroll
      for (int i = 0; i < 4; ++i) {
        int idx = t + 256 * i;
        Bs[nxt][idx & 31][idx >> 5] = rb[i];
      }
      cur = nxt;
    }
    __syncthreads();   // single barrier per step (writes to nxt can't alias reads of cur)
  }
  float2 bias = *(const float2*)&bi[o0 + tc * 2];
#pragma unroll
  for (int i = 0; i < 4; ++i) {
    int r = r0 + tr * 4 + i;
    if (r < 300) {
      float2 v;
      v.x = fmaxf(acc[i][0] + bias.x, 0.f);
      v.y = fmaxf(acc[i][1] + bias.y, 0.f);
      *(float2*)&feat[r * 2048 + o0 + tc * 2] = v;
    }
  }
}

// ---------------- Kernel 8: FC2 heads + softmax + per-class decode (fused) ----------------
__global__ __launch_bounds__(256) void k_fc2(const float* __restrict__ feat,
                                             const float* __restrict__ Wc,
                                             const float* __restrict__ bc,
                                             const float* __restrict__ Wb,
                                             const float* __restrict__ bb,
                                             const float* __restrict__ rois_xy,
                                             const float* __restrict__ validf,
                                             float* __restrict__ db2,
                                             float* __restrict__ msc2) {
  int r = blockIdx.x;
  int t = threadIdx.x;
  int l = t & 63, w = t >> 6;
  __shared__ float frow[2048];
  __shared__ float s_logit[20];
  __shared__ float s_probs[4];
  for (int i = t; i < 512; i += 256)
    ((float4*)frow)[i] = ((const float4*)(feat + r * 2048))[i];
  __syncthreads();
  for (int o = w; o < 20; o += 4) {
    const float* wr = (o < 4) ? (Wc + o * 2048) : (Wb + (o - 4) * 2048);
    float p = 0.f;
#pragma unroll
    for (int j = 0; j < 8; ++j) {
      float4 wv = ((const float4*)wr)[l + 64 * j];
      float4 fv = ((const float4*)frow)[l + 64 * j];
      p += wv.x * fv.x + wv.y * fv.y + wv.z * fv.z + wv.w * fv.w;
    }
    for (int off = 32; off > 0; off >>= 1) p += __shfl_xor(p, off);
    if (l == 0) s_logit[o] = p + ((o < 4) ? bc[o] : bb[o - 4]);
  }
  __syncthreads();
  if (t == 0) {
    float m = fmaxf(fmaxf(s_logit[0], s_logit[1]), fmaxf(s_logit[2], s_logit[3]));
    float e0 = expf(s_logit[0] - m), e1 = expf(s_logit[1] - m);
    float e2 = expf(s_logit[2] - m), e3 = expf(s_logit[3] - m);
    float ssum = e0 + e1 + e2 + e3;
    s_probs[0] = e0 / ssum; s_probs[1] = e1 / ssum;
    s_probs[2] = e2 / ssum; s_probs[3] = e3 / ssum;
  }
  __syncthreads();
  if (t < 3) {
    int c = t + 1;
    float x1 = rois_xy[r * 4 + 0], y1 = rois_xy[r * 4 + 1];
    float x2 = rois_xy[r * 4 + 2], y2 = rois_xy[r * 4 + 3];
    float rwv = x2 - x1 + 1.0f, rhv = y2 - y1 + 1.0f;
    float rcx = x1 + 0.5f * (rwv - 1.0f), rcy = y1 + 0.5f * (rhv - 1.0f);
    float t0 = s_logit[4 + 4 * c + 0] * 0.1f;
    float t1 = s_logit[4 + 4 * c + 1] * 0.1f;
    float t2 = s_logit[4 + 4 * c + 2] * 0.2f;
    float t3 = s_logit[4 + 4 * c + 3] * 0.2f;
    float cx = t0 * rwv + rcx, cy = t1 * rhv + rcy;
    float bw = expf(t2) * rwv, bh = expf(t3) * rhv;
    float dx1 = clipc(cx - 0.5f * (bw - 1.0f));
    float dy1 = clipc(cy - 0.5f * (bh - 1.0f));
    float dx2 = clipc(cx + 0.5f * (bw - 1.0f));
    float dy2 = clipc(cy + 0.5f * (bh - 1.0f));
    float dw = dx2 - dx1 + 1.0f, dh = dy2 - dy1 + 1.0f;
    float sc = s_probs[c];
    bool objok = (1.0f - s_probs[0]) >= 0.1f;
    bool valid = validf[r] > 0.5f;
    bool kf = valid && objok && (sc >= 0.1f) && ((dw >= (float)8.8008) || (dh >= (float)8.8008));
    int i2 = (c - 1) * 300 + r;
    db2[i2 * 4 + 0] = dx1; db2[i2 * 4 + 1] = dy1;
    db2[i2 * 4 + 2] = dx2; db2[i2 * 4 + 3] = dy2;
    msc2[i2] = kf ? sc : -1.0f;
  }
}

// ---------------- Kernel 9: rank-sort 900 (padded, unrolled) + greedy NMS-5 ----------------
__global__ __launch_bounds__(1024) void k_nms2(const float* __restrict__ db2,
                                               const float* __restrict__ msc2,
                                               float* __restrict__ dout) {
  const int t = threadIdx.x;
  __shared__ unsigned long long lk[1024];
  __shared__ unsigned long long sk[1024];
  __shared__ float4 abox[5];
  __shared__ float aar[5];
  __shared__ int s_A;
  sk[t] = 0ull;
  lk[t] = (t < 900) ? (((unsigned long long)mapf(msc2[t]) << 10) | (unsigned)(1023 - t)) : 0ull;
  if (t == 0) s_A = 0;
  __syncthreads();
  if (t < 900) {
    unsigned long long kp = lk[t];
    int r = 0;
#pragma unroll 8
    for (int q = 0; q < 1024; ++q) r += (lk[q] > kp) ? 1 : 0;   // zero pads contribute 0
    sk[r] = kp;   // keys unique -> ranks unique
  }
  __syncthreads();
  if (t < 64) {
    int A = 0;
    for (int base = 0; base < TOPK2 && A < 5; base += 64) {
      unsigned headm = (unsigned)(sk[base] >> 10);
      if (headm <= 0x80000000u) break;
      int rank = base + t;
      unsigned long long key = sk[rank];
      unsigned mk = (unsigned)(key >> 10);
      bool active = (rank < TOPK2) && (mk > 0x80000000u);
      int idx = 1023 - (int)(key & 1023ull);
      float4 bx = make_float4(0.f, 0.f, 0.f, 0.f);
      float area = 0.f;
      if (active) {
        bx = ((const float4*)db2)[idx];
        area = (bx.z - bx.x + 1.0f) * (bx.w - bx.y + 1.0f);
      }
      bool alive = active;
      for (int a = 0; a < A; ++a) {
        float4 ab = abox[a];
        float iw = fmaxf(fminf(bx.z, ab.z) - fmaxf(bx.x, ab.x) + 1.0f, 0.0f);
        float ih = fmaxf(fminf(bx.w, ab.w) - fmaxf(bx.y, ab.y) + 1.0f, 0.0f);
        float inter = iw * ih;
        float iou = inter / (area + aar[a] - inter);
        if (iou > 0.5f) { alive = false; break; }
      }
      unsigned long long bal = __ballot(alive);
      while (bal != 0ull && A < 5) {
        int j = __ffsll((long long)bal) - 1;
        float jx1 = __shfl(bx.x, j), jy1 = __shfl(bx.y, j);
        float jx2 = __shfl(bx.z, j), jy2 = __shfl(bx.w, j);
        float jar = __shfl(area, j);
        if (t == j) {
          abox[A] = bx; aar[A] = area;
          dout[A * 6 + 0] = bx.x; dout[A * 6 + 1] = bx.y;
          dout[A * 6 + 2] = bx.z; dout[A * 6 + 3] = bx.w;
          dout[A * 6 + 4] = unmapf(mk);
          dout[A * 6 + 5] = (float)(idx / 300 + 1);
        }
        if (alive) {
          float iw = fmaxf(fminf(bx.z, jx2) - fmaxf(bx.x, jx1) + 1.0f, 0.0f);
          float ih = fmaxf(fminf(bx.w, jy2) - fmaxf(bx.y, jy1) + 1.0f, 0.0f);
          float inter = iw * ih;
          float iou = inter / (area + jar - inter);
          if (iou > 0.5f || t == j) alive = false;
        }
        A++;
        bal = __ballot(alive);
      }
    }
    if (t == 0) s_A = A;
  }
  __syncthreads();
  int A = s_A;
  for (int z = A * 6 + t; z < 30; z += 1024) dout[z] = 0.f;
}

extern "C" void kernel_launch(void* const* d_in, const int* in_sizes, int n_in,
                              void* d_out, int out_size, void* d_ws, size_t ws_size,
                              hipStream_t stream) {
  const float* cls  = (const float*)d_in[0];
  const float* pred = (const float*)d_in[1];
  const float* ft   = (const float*)d_in[2];
  const float* Wi   = (const float*)d_in[3];
  const float* bi   = (const float*)d_in[4];
  const float* Wc   = (const float*)d_in[5];
  const float* bc   = (const float*)d_in[6];
  const float* Wb   = (const float*)d_in[7];
  const float* bb   = (const float*)d_in[8];
  float* out = (float*)d_out;
  float* w = (float*)d_ws;
  // layout (float offsets)
  float* boxes   = w;                                   // 0      .. 69360
  float* scores  = w + 69360;                           // 69360  .. 86700
  unsigned int* hist = (unsigned int*)(w + 86700);      // 86700  .. 103084
  unsigned int* cnt  = (unsigned int*)(w + 103084);     // 103084 (zeroed with hist)
  unsigned int* bcut = (unsigned int*)(w + 103085);     // 103085 (written by k_cutoff)
  unsigned long long* keys = (unsigned long long*)(w + 103088); // 4096 u64 -> 111280
  unsigned int* sscore = (unsigned int*)(w + 111280);   // 3000 u32 -> 114280
  float4* sbox   = (float4*)(w + 114280);               // 3008 f4 (padded) -> 126312
  float* rois_xy = w + 126312;                          // .. 127512
  float* validf  = w + 127512;                          // .. 127812
  float* pooledT = w + 127812;                          // 490*304=148960 -> 276772
  float* feat    = w + 276772;                          // 300*2048 -> 891172 (16B aligned)
  unsigned long long* mat = (unsigned long long*)(w + 276772); // aliases feat: 3008*48 u64
  float* db2     = w + 891172;                          // .. 894772 (16B aligned)
  float* msc2    = w + 894772;                          // .. 895672 (~3.58 MB)

  k_zero<<<65, 256, 0, stream>>>(hist);   // hist + cnt (replaces 38us runtime fill)
  k_decode<<<68, 256, 0, stream>>>(cls, pred, boxes, scores, hist);
  k_cutoff<<<1, 256, 0, stream>>>(hist, bcut);
  k_compact<<<68, 256, 0, stream>>>(scores, bcut, cnt, keys);
  k_sort<<<128, 256, 0, stream>>>(boxes, cnt, keys, sscore, sbox);
  k_iou<<<dim3(47, 47), 64, 0, stream>>>(sbox, mat);
  k_nms1<<<1, 256, 0, stream>>>(sscore, sbox, mat, out, rois_xy, validf);
  k_psroi<<<300, 256, 0, stream>>>(ft, rois_xy, pooledT);
  k_fc1<<<320, 256, 0, stream>>>(pooledT, Wi, bi, feat);
  k_fc2<<<300, 256, 0, stream>>>(feat, Wc, bc, Wb, bb, rois_xy, validf, db2, msc2);
  k_nms2<<<1, 1024, 0, stream>>>(db2, msc2, out);
}